// Round 1
// baseline (239.094 us; speedup 1.0000x reference)
//
#include <hip/hip_runtime.h>

namespace {

constexpr int Hdim = 512, Wdim = 512, NPLANE = 48;   // 16 B x 3 C planes
constexpr int TW = 64, TH = 16, RAD = 5, WS = 11;
constexpr int SROWS = TH + 2 * RAD;   // 26 staged rows
constexpr int SCOLS = TW + 2 * RAD;   // 74 staged cols
constexpr int SSTR  = 76;             // staging stride (mult of 4 for b128 aligned reads)
constexpr int HSTR  = 64;             // h-array stride (swizzled, conflict-free)
constexpr float C1c = 1e-4f;          // (0.01*1.0)^2
constexpr float C2c = 9e-4f;          // (0.03*1.0)^2

__device__ __forceinline__ float rcp_fast(float x) { return __builtin_amdgcn_rcpf(x); }

__global__ __launch_bounds__(256, 2) void ssim_map_kernel(
    const float* __restrict__ img1,
    const float* __restrict__ img2,
    const float* __restrict__ kern,
    float* __restrict__ out)
{
    __shared__ float sx1[SROWS * SSTR];
    __shared__ float sx2[SROWS * SSTR];
    __shared__ float hb[5][SROWS * HSTR];   // mu1,mu2,E11,E22,E12 after horizontal conv

    const int tid  = threadIdx.x;
    const int col0 = blockIdx.x * TW;
    const int row0 = blockIdx.y * TH;
    const long pbase = (long)blockIdx.z * (long)(Hdim * Wdim);

    // ---- recover 1D gaussian from 2D kernel: g[j] = k[5][j] / sum(k[5][:]) ----
    float g[WS];
    {
        float s = 0.f;
#pragma unroll
        for (int j = 0; j < WS; ++j) s += kern[RAD * WS + j];
        const float inv = 1.0f / s;
#pragma unroll
        for (int j = 0; j < WS; ++j) g[j] = kern[RAD * WS + j] * inv;
    }

    // ---- stage haloed x1, x2 into LDS with reflect padding ----
    for (int i = tid; i < SROWS * SCOLS; i += 256) {
        const int r = i / SCOLS;          // const-div -> magic multiply
        const int c = i - r * SCOLS;
        int gr = row0 - RAD + r;
        gr = (gr < 0) ? -gr : gr;
        gr = (gr >= Hdim) ? (2 * Hdim - 2 - gr) : gr;
        int gc = col0 - RAD + c;
        gc = (gc < 0) ? -gc : gc;
        gc = (gc >= Wdim) ? (2 * Wdim - 2 - gc) : gc;
        const long off = pbase + (long)gr * Wdim + gc;
        sx1[r * SSTR + c] = img1[off];
        sx2[r * SSTR + c] = img2[off];
    }
    __syncthreads();

    // ---- horizontal pass: 1D conv along cols of 5 quantities; 4 out-cols/lane ----
    for (int t = tid; t < SROWS * (TW / 4); t += 256) {
        const int row = t >> 4;
        const int q   = t & 15;           // out cols 4q..4q+3
        float a[16], b[16];
        const float4* pa = (const float4*)&sx1[row * SSTR + 4 * q];
        const float4* pb = (const float4*)&sx2[row * SSTR + 4 * q];
#pragma unroll
        for (int u = 0; u < 4; ++u) {
            const float4 va = pa[u], vb = pb[u];
            a[4*u+0] = va.x; a[4*u+1] = va.y; a[4*u+2] = va.z; a[4*u+3] = va.w;
            b[4*u+0] = vb.x; b[4*u+1] = vb.y; b[4*u+2] = vb.z; b[4*u+3] = vb.w;
        }
        float p11[14], p22[14], p12[14];
#pragma unroll
        for (int u = 0; u < 14; ++u) {
            p11[u] = a[u] * a[u];
            p22[u] = b[u] * b[u];
            p12[u] = a[u] * b[u];
        }
        float h1[4] = {0,0,0,0}, h2[4] = {0,0,0,0};
        float h11[4] = {0,0,0,0}, h22[4] = {0,0,0,0}, h12[4] = {0,0,0,0};
#pragma unroll
        for (int k = 0; k < WS; ++k) {
            const float w = g[k];
#pragma unroll
            for (int j = 0; j < 4; ++j) {
                h1[j]  = fmaf(w, a[j + k],   h1[j]);
                h2[j]  = fmaf(w, b[j + k],   h2[j]);
                h11[j] = fmaf(w, p11[j + k], h11[j]);
                h22[j] = fmaf(w, p22[j + k], h22[j]);
                h12[j] = fmaf(w, p12[j + k], h12[j]);
            }
        }
        // XOR swizzle keeps vertical-pass strided float4 reads conflict-free
        const int wc = row * HSTR + ((4 * q) ^ (4 * (row & 7)));
        *(float4*)&hb[0][wc] = make_float4(h1[0],  h1[1],  h1[2],  h1[3]);
        *(float4*)&hb[1][wc] = make_float4(h2[0],  h2[1],  h2[2],  h2[3]);
        *(float4*)&hb[2][wc] = make_float4(h11[0], h11[1], h11[2], h11[3]);
        *(float4*)&hb[3][wc] = make_float4(h22[0], h22[1], h22[2], h22[3]);
        *(float4*)&hb[4][wc] = make_float4(h12[0], h12[1], h12[2], h12[3]);
    }
    __syncthreads();

    // ---- vertical pass + SSIM epilogue: 1 row x 4 cols per thread ----
    {
        const int q  = tid & 15;
        const int rp = tid >> 4;          // output row within tile (0..15)
        float A[5][4];
#pragma unroll
        for (int m = 0; m < 5; ++m)
#pragma unroll
            for (int j = 0; j < 4; ++j) A[m][j] = 0.f;

#pragma unroll
        for (int k = 0; k < WS; ++k) {
            const int hr = rp + k;
            const int cc = hr * HSTR + ((4 * q) ^ (4 * (hr & 7)));
            const float w = g[k];
#pragma unroll
            for (int m = 0; m < 5; ++m) {
                const float4 v = *(const float4*)&hb[m][cc];
                A[m][0] = fmaf(w, v.x, A[m][0]);
                A[m][1] = fmaf(w, v.y, A[m][1]);
                A[m][2] = fmaf(w, v.z, A[m][2]);
                A[m][3] = fmaf(w, v.w, A[m][3]);
            }
        }

        float res[4];
#pragma unroll
        for (int j = 0; j < 4; ++j) {
            const float m1  = A[0][j], m2 = A[1][j];
            const float m1s = m1 * m1, m2s = m2 * m2, m12 = m1 * m2;
            const float sg1 = A[2][j] - m1s;
            const float sg2 = A[3][j] - m2s;
            const float sg12 = A[4][j] - m12;
            const float num = (2.f * m12 + C1c) * (2.f * sg12 + C2c);
            const float den = (m1s + m2s + C1c) * (sg1 + sg2 + C2c);
            res[j] = num * rcp_fast(den);
        }
        float4* po = (float4*)&out[pbase + (long)(row0 + rp) * Wdim + col0 + 4 * q];
        *po = make_float4(res[0], res[1], res[2], res[3]);
    }
}

} // namespace

extern "C" void kernel_launch(void* const* d_in, const int* in_sizes, int n_in,
                              void* d_out, int out_size, void* d_ws, size_t ws_size,
                              hipStream_t stream) {
    const float* img1 = (const float*)d_in[0];
    const float* img2 = (const float*)d_in[1];
    const float* kern = (const float*)d_in[2];
    float* out = (float*)d_out;
    dim3 grid(Wdim / TW, Hdim / TH, NPLANE);
    ssim_map_kernel<<<grid, dim3(256), 0, stream>>>(img1, img2, kern, out);
}

// Round 2
// 174.624 us; speedup vs baseline: 1.3692x; 1.3692x over previous
//
#include <hip/hip_runtime.h>

namespace {

constexpr int Hd = 512, Wd = 512;
constexpr int TH = 32;            // output rows per block
constexpr int G  = 4;             // output rows per group (barrier period)
constexpr int NG = TH / G;        // 8 groups
constexpr int RAD = 5, WS = 11;
constexpr int NIN = G + WS - 1;   // 14 input rows per group
constexpr int HSTR = 524;         // 5 + 512 + 5 = 522 used, padded to mult of 4
constexpr float C1c = 1e-4f;      // (0.01*1.0)^2
constexpr float C2c = 9e-4f;      // (0.03*1.0)^2

__device__ __forceinline__ float rcp_fast(float x) { return __builtin_amdgcn_rcpf(x); }

__global__ __launch_bounds__(512, 2) void ssim_map_kernel(
    const float* __restrict__ img1,
    const float* __restrict__ img2,
    const float* __restrict__ kern,
    float* __restrict__ out)
{
    // 5 quantities x G rows x (512 + 10 halo) of vertically-convolved data
    __shared__ float hbuf[5 * G * HSTR];   // 41.9 KB

    const int tid   = threadIdx.x;
    const int row0  = blockIdx.x * TH;
    const long pbase = (long)blockIdx.y * (long)(Hd * Wd);

    // ---- recover 1D gaussian: g[j] = k[5][j] / sum(k[5][:])  (uniform -> SALU) ----
    float g[WS];
    {
        float s = 0.f;
#pragma unroll
        for (int j = 0; j < WS; ++j) s += kern[RAD * WS + j];
        const float inv = 1.0f / s;
#pragma unroll
        for (int j = 0; j < WS; ++j) g[j] = kern[RAD * WS + j] * inv;
    }

    const int c  = tid;          // vertical phase: one column per thread
    const int hr = tid >> 7;     // horizontal phase: row within group (0..3)
    const int hu = tid & 127;    // horizontal phase: item -> out cols 4hu..4hu+3

    for (int grp = 0; grp < NG; ++grp) {
        // ================= vertical pass (global -> registers) =================
        float acc[5][G];
#pragma unroll
        for (int q = 0; q < 5; ++q)
#pragma unroll
            for (int r = 0; r < G; ++r) acc[q][r] = 0.f;

        const int ibase = row0 + grp * G - RAD;   // first input row (uniform)
#pragma unroll
        for (int j = 0; j < NIN; ++j) {
            int gr = ibase + j;                    // uniform -> SALU reflect
            gr = (gr < 0) ? -gr : gr;
            gr = (gr >= Hd) ? (2 * Hd - 2 - gr) : gr;
            const long off = pbase + (long)gr * Wd + c;
            const float a = img1[off];
            const float b = img2[off];
            const float p11 = a * a, p22 = b * b, p12 = a * b;
#pragma unroll
            for (int r = 0; r < G; ++r) {
                const int k = j - r;               // tap index, compile-time
                if (k >= 0 && k < WS) {
                    const float w = g[k];
                    acc[0][r] = fmaf(w, a,   acc[0][r]);
                    acc[1][r] = fmaf(w, b,   acc[1][r]);
                    acc[2][r] = fmaf(w, p11, acc[2][r]);
                    acc[3][r] = fmaf(w, p22, acc[3][r]);
                    acc[4][r] = fmaf(w, p12, acc[4][r]);
                }
            }
        }

        // previous group's horizontal reads must finish before overwriting hbuf
        __syncthreads();

        // write vertically-convolved rows (stride-1 b32, conflict-free)
#pragma unroll
        for (int q = 0; q < 5; ++q)
#pragma unroll
            for (int r = 0; r < G; ++r)
                hbuf[(q * G + r) * HSTR + RAD + c] = acc[q][r];

        // reflect column halo: col -k (k=1..5) = col k ; col 511+k = col 511-k
        if (c >= 1 && c <= RAD) {
#pragma unroll
            for (int q = 0; q < 5; ++q)
#pragma unroll
                for (int r = 0; r < G; ++r)
                    hbuf[(q * G + r) * HSTR + RAD - c] = acc[q][r];
        } else if (c >= Wd - 1 - RAD && c <= Wd - 2) {
            // holds value of col c = 511-k -> halo index RAD + 1022 - c
#pragma unroll
            for (int q = 0; q < 5; ++q)
#pragma unroll
                for (int r = 0; r < G; ++r)
                    hbuf[(q * G + r) * HSTR + RAD + 1022 - c] = acc[q][r];
        }

        __syncthreads();

        // ================= horizontal pass + epilogue =================
        // item needs buffer floats [4hu .. 4hu+13] (cols 4hu-5 .. 4hu+8)
        float hq[5][4];
#pragma unroll
        for (int q = 0; q < 5; ++q) {
            const float* base = &hbuf[(q * G + hr) * HSTR + 4 * hu];
            const float4 v0 = *(const float4*)(base);
            const float4 v1 = *(const float4*)(base + 4);
            const float4 v2 = *(const float4*)(base + 8);
            const float2 v3 = *(const float2*)(base + 12);
            const float f[14] = { v0.x, v0.y, v0.z, v0.w,
                                  v1.x, v1.y, v1.z, v1.w,
                                  v2.x, v2.y, v2.z, v2.w,
                                  v3.x, v3.y };
            float h0 = 0.f, h1 = 0.f, h2 = 0.f, h3 = 0.f;
#pragma unroll
            for (int k = 0; k < WS; ++k) {
                const float w = g[k];
                h0 = fmaf(w, f[k],     h0);
                h1 = fmaf(w, f[k + 1], h1);
                h2 = fmaf(w, f[k + 2], h2);
                h3 = fmaf(w, f[k + 3], h3);
            }
            hq[q][0] = h0; hq[q][1] = h1; hq[q][2] = h2; hq[q][3] = h3;
        }

        float res[4];
#pragma unroll
        for (int j = 0; j < 4; ++j) {
            const float m1 = hq[0][j], m2 = hq[1][j];
            const float m1s = m1 * m1, m2s = m2 * m2, m12 = m1 * m2;
            const float sg1 = hq[2][j] - m1s;
            const float sg2 = hq[3][j] - m2s;
            const float sg12 = hq[4][j] - m12;
            const float num = (2.f * m12 + C1c) * (2.f * sg12 + C2c);
            const float den = (m1s + m2s + C1c) * (sg1 + sg2 + C2c);
            res[j] = num * rcp_fast(den);
        }
        float4* po = (float4*)&out[pbase + (long)(row0 + grp * G + hr) * Wd + 4 * hu];
        *po = make_float4(res[0], res[1], res[2], res[3]);
    }
}

} // namespace

extern "C" void kernel_launch(void* const* d_in, const int* in_sizes, int n_in,
                              void* d_out, int out_size, void* d_ws, size_t ws_size,
                              hipStream_t stream) {
    const float* img1 = (const float*)d_in[0];
    const float* img2 = (const float*)d_in[1];
    const float* kern = (const float*)d_in[2];
    float* outp = (float*)d_out;
    dim3 grid(Hd / TH, 48);   // 16 row-bands x (16 B x 3 C) planes = 768 blocks
    ssim_map_kernel<<<grid, dim3(512), 0, stream>>>(img1, img2, kern, outp);
}